// Round 7
// baseline (1918.629 us; speedup 1.0000x reference)
//
#include <hip/hip_runtime.h>
#include <math.h>

#define D 32
#define BN_EPS 1e-5f
#define NRANGE 256      // dst ranges; RW = ceil(N/NRANGE) nodes each
#define EPB 4096        // edges per block in build_part (LDS sort capacity)
#define K1_TPB 256
#define SPLIT 2         // sub-blocks per range in layer kernels
#define L_TPB 1024
#define NG (L_TPB / 32) // 32-lane edge groups per layer block

// ============ K1: partition edges into per-range segments, coalesced writes ============
__global__ void build_part(const int* __restrict__ src, const int* __restrict__ dst,
                           unsigned int* __restrict__ part, int* __restrict__ gcount,
                           int E, int cap, int RW, unsigned long long M) {
    __shared__ unsigned int sorted[EPB];
    __shared__ unsigned char rid[EPB];
    __shared__ int cnt[NRANGE];
    __shared__ int exc[NRANGE];
    __shared__ int cur[NRANGE];
    __shared__ int gbase[NRANGE];
    int t = threadIdx.x;
    cnt[t] = 0;                    // K1_TPB == NRANGE == 256
    __syncthreads();

    int base = blockIdx.x * EPB;
    int n = min(EPB, E - base);

    for (int i = t; i < n; i += K1_TPB) {
        int d = dst[base + i];
        int r = (int)(((unsigned long long)d * M) >> 40);
        atomicAdd(&cnt[r], 1);
    }
    __syncthreads();

    int inc = cnt[t];
    exc[t] = inc;
    __syncthreads();
    for (int s = 1; s < NRANGE; s <<= 1) {
        int u = (t >= s) ? exc[t - s] : 0;
        __syncthreads();
        exc[t] += u;
        __syncthreads();
    }
    int excl = exc[t] - cnt[t];
    __syncthreads();
    exc[t] = excl;
    cur[t] = excl;
    gbase[t] = atomicAdd(&gcount[t], cnt[t]);   // 1 global atomic per (block,range)
    __syncthreads();

    for (int i = t; i < n; i += K1_TPB) {
        int d = dst[base + i];
        int s = src[base + i];
        int r = (int)(((unsigned long long)d * M) >> 40);
        int dl = d - r * RW;
        int j = atomicAdd(&cur[r], 1);          // LDS
        sorted[j] = ((unsigned)dl << 17) | (unsigned)s;
        rid[j] = (unsigned char)r;
    }
    __syncthreads();

    for (int j = t; j < n; j += K1_TPB) {
        int r = rid[j];
        int pos = gbase[r] + (j - exc[r]);
        if (pos < cap) part[(size_t)r * cap + pos] = sorted[j];
    }
}

// ============ network ============
__global__ void compute_y(const float* __restrict__ x, const float* __restrict__ W1a,
                          float* __restrict__ y, int N) {
    long long gid = (long long)blockIdx.x * blockDim.x + threadIdx.x;
    int i = (int)(gid >> 5);
    int lane = (int)(gid & 31);
    if (i >= N) return;
    float x0 = x[i * 3 + 0], x1 = x[i * 3 + 1], x2 = x[i * 3 + 2];
    float t = x0 * W1a[0 * D + lane];
    t = fmaf(x1, W1a[1 * D + lane], t);
    t = fmaf(x2, W1a[2 * D + lane], t);
    y[(size_t)i * D + lane] = t;
}

// Layer consuming the range-partition directly: LDS agg (ds_add_f32) -> MLP -> BN.
// Block (half, r): owns nodes [r*RW + half*qn_full, +qn). Scans the whole segment,
// gathers only edges whose dl falls in its half.
template <bool SKIP_WA>
__global__ __launch_bounds__(L_TPB) void layer_part(
    const float* __restrict__ hin, const unsigned int* __restrict__ part,
    const int* __restrict__ gcount, int cap, int RW, int N,
    const float* __restrict__ Wa, const float* __restrict__ ba,
    const float* __restrict__ Wb, const float* __restrict__ bb,
    const float* __restrict__ g, const float* __restrict__ be,
    const float* __restrict__ m, const float* __restrict__ v,
    float* __restrict__ hout) {
    extern __shared__ float agg[];     // qn_full * 32 floats
    int r = blockIdx.y;
    int half = blockIdx.x;
    int qn_full = (RW + SPLIT - 1) / SPLIT;
    int qlo = half * qn_full;
    int qn = RW - qlo; if (qn > qn_full) qn = qn_full;
    if (qn <= 0) return;
    int t = threadIdx.x;
    int gidx = t >> 5;
    int lane = t & 31;
    int nbase = r * RW + qlo;

    // init agg with self term (eps=0)
    for (int nl = gidx; nl < qn; nl += NG) {
        int node = nbase + nl;
        agg[nl * D + lane] = (node < N) ? hin[(size_t)node * D + lane] : 0.f;
    }
    __syncthreads();

    int count = gcount[r]; if (count > cap) count = cap;
    const unsigned int* p = part + (size_t)r * cap;
    int full = (count / (4 * NG)) * (4 * NG);
    for (int i0 = gidx * 4; i0 < full; i0 += 4 * NG) {
        uint4 pk = *(const uint4*)(p + i0);   // 4 edges, broadcast across the group
        unsigned l0 = (pk.x >> 17) - qlo;
        unsigned l1 = (pk.y >> 17) - qlo;
        unsigned l2 = (pk.z >> 17) - qlo;
        unsigned l3 = (pk.w >> 17) - qlo;
        if (l0 < (unsigned)qn) atomicAdd(&agg[l0 * D + lane], hin[(size_t)(pk.x & 0x1FFFFu) * D + lane]);
        if (l1 < (unsigned)qn) atomicAdd(&agg[l1 * D + lane], hin[(size_t)(pk.y & 0x1FFFFu) * D + lane]);
        if (l2 < (unsigned)qn) atomicAdd(&agg[l2 * D + lane], hin[(size_t)(pk.z & 0x1FFFFu) * D + lane]);
        if (l3 < (unsigned)qn) atomicAdd(&agg[l3 * D + lane], hin[(size_t)(pk.w & 0x1FFFFu) * D + lane]);
    }
    for (int i = full + gidx; i < count; i += NG) {
        unsigned int pk = p[i];
        unsigned l0 = (pk >> 17) - qlo;
        if (l0 < (unsigned)qn) atomicAdd(&agg[l0 * D + lane], hin[(size_t)(pk & 0x1FFFFu) * D + lane]);
    }
    __syncthreads();

    // MLP + ReLU + BN per node, straight out of LDS
    for (int nl = gidx; nl < qn; nl += NG) {
        int node = nbase + nl;
        if (node >= N) continue;
        float acc = agg[nl * D + lane];
        float tv;
        if (SKIP_WA) {
            tv = fmaxf(acc + ba[lane], 0.f);
        } else {
            tv = ba[lane];
#pragma unroll
            for (int k = 0; k < D; k++) {
                float ak = __shfl(acc, k, D);
                tv = fmaf(ak, Wa[k * D + lane], tv);
            }
            tv = fmaxf(tv, 0.f);
        }
        float o = bb[lane];
#pragma unroll
        for (int j = 0; j < D; j++) {
            float tj = __shfl(tv, j, D);
            o = fmaf(tj, Wb[j * D + lane], o);
        }
        o = fmaxf(o, 0.f);
        hout[(size_t)node * D + lane] =
            g[lane] * (o - m[lane]) * rsqrtf(v[lane] + BN_EPS) + be[lane];
    }
}

__device__ __forceinline__ int lower_bound_i(const int* a, int n, int key) {
    int lo = 0, hi = n;
    while (lo < hi) {
        int mid = (lo + hi) >> 1;
        if (a[mid] < key) lo = mid + 1; else hi = mid;
    }
    return lo;
}

__global__ void pool_head(const float* __restrict__ h, const int* __restrict__ batch,
                          const float* __restrict__ Wf1, const float* __restrict__ bf1,
                          const float* __restrict__ Wf2, const float* __restrict__ bf2,
                          float* __restrict__ out, int N, int G) {
    long long gid = (long long)blockIdx.x * blockDim.x + threadIdx.x;
    int gi = (int)(gid >> 5);
    int lane = (int)(gid & 31);
    if (gi >= G) return;
    int lo = lower_bound_i(batch, N, gi);
    int hi = lower_bound_i(batch, N, gi + 1);
    float p = 0.f;
    for (int n = lo; n < hi; n++) p += h[(size_t)n * D + lane];
    float q = bf1[lane];
#pragma unroll
    for (int j = 0; j < D; j++) {
        float pj = __shfl(p, j, D);
        q = fmaf(pj, Wf1[j * D + lane], q);
    }
    q = fmaxf(q, 0.f);
    float r = q * Wf2[lane];
#pragma unroll
    for (int off = 16; off; off >>= 1) r += __shfl_xor(r, off, D);
    if (lane == 0) out[gi] = tanhf(r + bf2[0]);
}

extern "C" void kernel_launch(void* const* d_in, const int* in_sizes, int n_in,
                              void* d_out, int out_size, void* d_ws, size_t ws_size,
                              hipStream_t stream) {
    const float* x = (const float*)d_in[0];
    const int* ei = (const int*)d_in[1];
    const int* batch = (const int*)d_in[2];
    const int E = in_sizes[1] / 2;
    const int N = in_sizes[2];
    const int G = out_size;
    const int* src = ei;
    const int* dst = ei + E;

    const float* P[3][8];
    for (int l = 0; l < 3; l++)
        for (int k = 0; k < 8; k++) P[l][k] = (const float*)d_in[3 + 8 * l + k];
    const float* Wf1 = (const float*)d_in[27];
    const float* bf1 = (const float*)d_in[28];
    const float* Wf2 = (const float*)d_in[29];
    const float* bf2 = (const float*)d_in[30];

    const int RW = (N + NRANGE - 1) / NRANGE;                    // 391 for N=100K
    const unsigned long long M = ((1ull << 40) + RW - 1) / RW;   // magic div by RW
    int mean = (E + NRANGE - 1) / NRANGE;
    int cap = mean + mean / 16 + 64;   // ~+7 sigma slack, Binomial(E, 1/256)
    cap = (cap + 3) & ~3;              // 16B alignment for uint4 segment reads

    // workspace layout (4B units): h0, h1, part, gcount (~39.3 MB total)
    float* ws = (float*)d_ws;
    size_t off = 0;
    float* h0 = ws + off; off += (size_t)N * D;
    float* h1 = ws + off; off += (size_t)N * D;
    unsigned int* part = (unsigned int*)(ws + off); off += (size_t)NRANGE * cap;
    int* gcount = (int*)(ws + off); off += NRANGE;

    const int B = 256;
    long long tN32 = (long long)N * D;
    int nbp = (E + EPB - 1) / EPB;
    int qn_full = (RW + SPLIT - 1) / SPLIT;
    size_t shbytes = (size_t)qn_full * D * sizeof(float);
    dim3 lgrid(SPLIT, NRANGE);

    // ---- partition build (only preprocessing kernel) ----
    hipMemsetAsync(gcount, 0, NRANGE * sizeof(int), stream);
    build_part<<<nbp, K1_TPB, 0, stream>>>(src, dst, part, gcount, E, cap, RW, M);

    // ---- layer 1 (y-space: (x+agg_x)@W1a == y+agg_y, y=x@W1a) ----
    compute_y<<<(int)((tN32 + B - 1) / B), B, 0, stream>>>(x, P[0][0], h0, N);
    layer_part<true><<<lgrid, L_TPB, shbytes, stream>>>(
        h0, part, gcount, cap, RW, N, P[0][0], P[0][1], P[0][2], P[0][3],
        P[0][4], P[0][5], P[0][6], P[0][7], h1);

    // ---- layer 2: h1 -> h0 ----
    layer_part<false><<<lgrid, L_TPB, shbytes, stream>>>(
        h1, part, gcount, cap, RW, N, P[1][0], P[1][1], P[1][2], P[1][3],
        P[1][4], P[1][5], P[1][6], P[1][7], h0);

    // ---- layer 3: h0 -> h1 ----
    layer_part<false><<<lgrid, L_TPB, shbytes, stream>>>(
        h0, part, gcount, cap, RW, N, P[2][0], P[2][1], P[2][2], P[2][3],
        P[2][4], P[2][5], P[2][6], P[2][7], h1);

    // ---- fused pool + head ----
    pool_head<<<(int)(((long long)G * D + B - 1) / B), B, 0, stream>>>(
        h1, batch, Wf1, bf1, Wf2, bf2, (float*)d_out, N, G);
}

// Round 8
// 1864.922 us; speedup vs baseline: 1.0288x; 1.0288x over previous
//
#include <hip/hip_runtime.h>
#include <math.h>

#define D 32
#define BN_EPS 1e-5f
#define NRANGE 512      // dst ranges; RW = ceil(N/NRANGE) nodes each (196 @ N=100K)
#define EPB 4096        // edges per block in build_part
#define K1_TPB 512
#define EPT (EPB / K1_TPB)   // 8 edges per thread, register-carried
#define L_TPB 1024
#define NG2 (L_TPB / 32)     // 32 edge-groups per layer block

// ============ K1: partition edges into per-range segments, register-carried ============
__global__ __launch_bounds__(K1_TPB) void build_part(
    const int* __restrict__ src, const int* __restrict__ dst,
    unsigned int* __restrict__ part, int* __restrict__ gcount,
    int E, int cap, int RW, unsigned long long M) {
    __shared__ unsigned int sorted[EPB];
    __shared__ unsigned short rid[EPB];
    __shared__ int cnt[NRANGE];
    __shared__ int exc[NRANGE];
    __shared__ int cur[NRANGE];
    __shared__ int gbase[NRANGE];
    int t = threadIdx.x;
    cnt[t] = 0;                      // K1_TPB == NRANGE == 512
    __syncthreads();

    int base = blockIdx.x * EPB;
    int n = min(EPB, E - base);

    // pass A: load edges into registers, count ranges
    unsigned int mypk[EPT];
    unsigned short myr[EPT];
#pragma unroll
    for (int k = 0; k < EPT; k++) {
        int i = t + k * K1_TPB;
        if (i < n) {
            int d = dst[base + i];
            int s = src[base + i];
            int r = (int)(((unsigned long long)d * M) >> 40);
            mypk[k] = ((unsigned)(d - r * RW) << 17) | (unsigned)s;
            myr[k] = (unsigned short)r;
            atomicAdd(&cnt[r], 1);
        } else myr[k] = 0xFFFFu;
    }
    __syncthreads();

    // inclusive Hillis-Steele scan over 512 bins -> exclusive prefix
    int inc = cnt[t];
    exc[t] = inc;
    __syncthreads();
    for (int s = 1; s < NRANGE; s <<= 1) {
        int u = (t >= s) ? exc[t - s] : 0;
        __syncthreads();
        exc[t] += u;
        __syncthreads();
    }
    int excl = exc[t] - cnt[t];
    __syncthreads();
    exc[t] = excl;
    cur[t] = excl;
    gbase[t] = atomicAdd(&gcount[t], cnt[t]);   // 1 global atomic per (block,range)
    __syncthreads();

    // pass B: scatter registers into LDS sorted-by-range
#pragma unroll
    for (int k = 0; k < EPT; k++) {
        if (myr[k] != 0xFFFFu) {
            int j = atomicAdd(&cur[myr[k]], 1);  // LDS
            sorted[j] = mypk[k];
            rid[j] = myr[k];
        }
    }
    __syncthreads();

    // write phase: linear stream out of LDS -> coalesced runs per range
    for (int j = t; j < n; j += K1_TPB) {
        int r = rid[j];
        int pos = gbase[r] + (j - exc[r]);
        if (pos < cap) part[(size_t)r * cap + pos] = sorted[j];
    }
}

// ============ network ============
__global__ void compute_y(const float* __restrict__ x, const float* __restrict__ W1a,
                          float* __restrict__ y, int N) {
    long long gid = (long long)blockIdx.x * blockDim.x + threadIdx.x;
    int i = (int)(gid >> 5);
    int lane = (int)(gid & 31);
    if (i >= N) return;
    float x0 = x[i * 3 + 0], x1 = x[i * 3 + 1], x2 = x[i * 3 + 2];
    float t = x0 * W1a[0 * D + lane];
    t = fmaf(x1, W1a[1 * D + lane], t);
    t = fmaf(x2, W1a[2 * D + lane], t);
    y[(size_t)i * D + lane] = t;
}

// One block per range: LDS agg init w/ self term, branch-free 8-wide gather+ds_add,
// then MLP+BN straight out of LDS. No col/deg structures needed.
template <bool SKIP_WA>
__global__ __launch_bounds__(L_TPB, 8) void layer_agg(
    const float* __restrict__ hin, const unsigned int* __restrict__ part,
    const int* __restrict__ gcount, int cap, int RW, int N,
    const float* __restrict__ Wa, const float* __restrict__ ba,
    const float* __restrict__ Wb, const float* __restrict__ bb,
    const float* __restrict__ g, const float* __restrict__ be,
    const float* __restrict__ m, const float* __restrict__ v,
    float* __restrict__ hout) {
    extern __shared__ float agg[];     // RW * 32 floats (~25 KB)
    int r = blockIdx.x;
    int t = threadIdx.x;
    int gidx = t >> 5;
    int lane = t & 31;
    int nbase = r * RW;

    for (int nl = gidx; nl < RW; nl += NG2) {
        int node = nbase + nl;
        agg[nl * D + lane] = (node < N) ? hin[(size_t)node * D + lane] : 0.f;
    }
    __syncthreads();

    int count = gcount[r]; if (count > cap) count = cap;
    const unsigned int* p = part + (size_t)r * cap;
    const int per = 8 * NG2;           // 256 edges per block-iteration
    int full = (count / per) * per;
    for (int i0 = gidx * 8; i0 < full; i0 += per) {
        uint4 a = *(const uint4*)(p + i0);       // broadcast reads
        uint4 b = *(const uint4*)(p + i0 + 4);
        float v0 = hin[(size_t)(a.x & 0x1FFFFu) * D + lane];
        float v1 = hin[(size_t)(a.y & 0x1FFFFu) * D + lane];
        float v2 = hin[(size_t)(a.z & 0x1FFFFu) * D + lane];
        float v3 = hin[(size_t)(a.w & 0x1FFFFu) * D + lane];
        float v4 = hin[(size_t)(b.x & 0x1FFFFu) * D + lane];
        float v5 = hin[(size_t)(b.y & 0x1FFFFu) * D + lane];
        float v6 = hin[(size_t)(b.z & 0x1FFFFu) * D + lane];
        float v7 = hin[(size_t)(b.w & 0x1FFFFu) * D + lane];
        atomicAdd(&agg[(a.x >> 17) * D + lane], v0);   // ds_add_f32, lane=bank
        atomicAdd(&agg[(a.y >> 17) * D + lane], v1);
        atomicAdd(&agg[(a.z >> 17) * D + lane], v2);
        atomicAdd(&agg[(a.w >> 17) * D + lane], v3);
        atomicAdd(&agg[(b.x >> 17) * D + lane], v4);
        atomicAdd(&agg[(b.y >> 17) * D + lane], v5);
        atomicAdd(&agg[(b.z >> 17) * D + lane], v6);
        atomicAdd(&agg[(b.w >> 17) * D + lane], v7);
    }
    for (int i = full + gidx; i < count; i += NG2) {
        unsigned int pk = p[i];
        atomicAdd(&agg[(pk >> 17) * D + lane], hin[(size_t)(pk & 0x1FFFFu) * D + lane]);
    }
    __syncthreads();

    for (int nl = gidx; nl < RW; nl += NG2) {
        int node = nbase + nl;
        if (node >= N) continue;
        float acc = agg[nl * D + lane];
        float tv;
        if (SKIP_WA) {
            tv = fmaxf(acc + ba[lane], 0.f);
        } else {
            tv = ba[lane];
#pragma unroll
            for (int k = 0; k < D; k++) {
                float ak = __shfl(acc, k, D);
                tv = fmaf(ak, Wa[k * D + lane], tv);
            }
            tv = fmaxf(tv, 0.f);
        }
        float o = bb[lane];
#pragma unroll
        for (int j = 0; j < D; j++) {
            float tj = __shfl(tv, j, D);
            o = fmaf(tj, Wb[j * D + lane], o);
        }
        o = fmaxf(o, 0.f);
        hout[(size_t)node * D + lane] =
            g[lane] * (o - m[lane]) * rsqrtf(v[lane] + BN_EPS) + be[lane];
    }
}

__device__ __forceinline__ int lower_bound_i(const int* a, int n, int key) {
    int lo = 0, hi = n;
    while (lo < hi) {
        int mid = (lo + hi) >> 1;
        if (a[mid] < key) lo = mid + 1; else hi = mid;
    }
    return lo;
}

__global__ void pool_head(const float* __restrict__ h, const int* __restrict__ batch,
                          const float* __restrict__ Wf1, const float* __restrict__ bf1,
                          const float* __restrict__ Wf2, const float* __restrict__ bf2,
                          float* __restrict__ out, int N, int G) {
    long long gid = (long long)blockIdx.x * blockDim.x + threadIdx.x;
    int gi = (int)(gid >> 5);
    int lane = (int)(gid & 31);
    if (gi >= G) return;
    int lo = lower_bound_i(batch, N, gi);
    int hi = lower_bound_i(batch, N, gi + 1);
    float p = 0.f;
    for (int n = lo; n < hi; n++) p += h[(size_t)n * D + lane];
    float q = bf1[lane];
#pragma unroll
    for (int j = 0; j < D; j++) {
        float pj = __shfl(p, j, D);
        q = fmaf(pj, Wf1[j * D + lane], q);
    }
    q = fmaxf(q, 0.f);
    float r = q * Wf2[lane];
#pragma unroll
    for (int off = 16; off; off >>= 1) r += __shfl_xor(r, off, D);
    if (lane == 0) out[gi] = tanhf(r + bf2[0]);
}

extern "C" void kernel_launch(void* const* d_in, const int* in_sizes, int n_in,
                              void* d_out, int out_size, void* d_ws, size_t ws_size,
                              hipStream_t stream) {
    const float* x = (const float*)d_in[0];
    const int* ei = (const int*)d_in[1];
    const int* batch = (const int*)d_in[2];
    const int E = in_sizes[1] / 2;
    const int N = in_sizes[2];
    const int G = out_size;
    const int* src = ei;
    const int* dst = ei + E;

    const float* P[3][8];
    for (int l = 0; l < 3; l++)
        for (int k = 0; k < 8; k++) P[l][k] = (const float*)d_in[3 + 8 * l + k];
    const float* Wf1 = (const float*)d_in[27];
    const float* bf1 = (const float*)d_in[28];
    const float* Wf2 = (const float*)d_in[29];
    const float* bf2 = (const float*)d_in[30];

    const int RW = (N + NRANGE - 1) / NRANGE;                    // 196 @ N=100K
    const unsigned long long M = ((1ull << 40) + RW - 1) / RW;   // magic div by RW
    int mean = (E + NRANGE - 1) / NRANGE;
    int cap = mean + mean / 8 + 64;    // ~+10 sigma slack, Binomial(E, 1/512)
    cap = (cap + 7) & ~7;              // alignment for uint4 segment reads

    // workspace (4B units): h0, h1, part, gcount (~40 MB, well under prior 58 MB use)
    float* ws = (float*)d_ws;
    size_t off = 0;
    float* h0 = ws + off; off += (size_t)N * D;
    float* h1 = ws + off; off += (size_t)N * D;
    unsigned int* part = (unsigned int*)(ws + off); off += (size_t)NRANGE * cap;
    int* gcount = (int*)(ws + off); off += NRANGE;

    const int B = 256;
    long long tN32 = (long long)N * D;
    int nbp = (E + EPB - 1) / EPB;
    size_t shbytes = (size_t)RW * D * sizeof(float);

    // ---- partition build (only preprocessing kernel) ----
    hipMemsetAsync(gcount, 0, NRANGE * sizeof(int), stream);
    build_part<<<nbp, K1_TPB, 0, stream>>>(src, dst, part, gcount, E, cap, RW, M);

    // ---- layer 1 (y-space: (x+agg_x)@W1a == y+agg_y, y=x@W1a) ----
    compute_y<<<(int)((tN32 + B - 1) / B), B, 0, stream>>>(x, P[0][0], h0, N);
    layer_agg<true><<<NRANGE, L_TPB, shbytes, stream>>>(
        h0, part, gcount, cap, RW, N, P[0][0], P[0][1], P[0][2], P[0][3],
        P[0][4], P[0][5], P[0][6], P[0][7], h1);

    // ---- layer 2: h1 -> h0 ----
    layer_agg<false><<<NRANGE, L_TPB, shbytes, stream>>>(
        h1, part, gcount, cap, RW, N, P[1][0], P[1][1], P[1][2], P[1][3],
        P[1][4], P[1][5], P[1][6], P[1][7], h0);

    // ---- layer 3: h0 -> h1 ----
    layer_agg<false><<<NRANGE, L_TPB, shbytes, stream>>>(
        h0, part, gcount, cap, RW, N, P[2][0], P[2][1], P[2][2], P[2][3],
        P[2][4], P[2][5], P[2][6], P[2][7], h1);

    // ---- fused pool + head ----
    pool_head<<<(int)(((long long)G * D + B - 1) / B), B, 0, stream>>>(
        h1, batch, Wf1, bf1, Wf2, bf2, (float*)d_out, N, G);
}

// Round 9
// 413.092 us; speedup vs baseline: 4.6446x; 4.5145x over previous
//
#include <hip/hip_runtime.h>
#include <math.h>

#define D 32
#define BN_EPS 1e-5f
#define NRANGE 256      // dst ranges; RW = ceil(N/NRANGE) nodes each (391 @ N=100K)
#define RWC 391         // compile-time RW bound (LDS sizing)
#define MAXD 80         // padded degree cap; Poisson(32): P(deg>80) ~ 5e-13/node
#define EPB 4096        // edges per block in build_part
#define K1_TPB 256

// ============ K1: partition edges into per-range segments, coalesced writes ============
__global__ void build_part(const int* __restrict__ src, const int* __restrict__ dst,
                           unsigned int* __restrict__ part, int* __restrict__ gcount,
                           int E, int cap, int RW, unsigned long long M) {
    __shared__ unsigned int sorted[EPB];
    __shared__ unsigned char rid[EPB];
    __shared__ int cnt[NRANGE];
    __shared__ int exc[NRANGE];
    __shared__ int cur[NRANGE];
    __shared__ int gbase[NRANGE];
    int t = threadIdx.x;
    cnt[t] = 0;                    // K1_TPB == NRANGE == 256
    __syncthreads();

    int base = blockIdx.x * EPB;
    int n = min(EPB, E - base);

    // pass A: count ranges
    for (int i = t; i < n; i += K1_TPB) {
        int d = dst[base + i];
        int r = (int)(((unsigned long long)d * M) >> 40);
        atomicAdd(&cnt[r], 1);
    }
    __syncthreads();

    // inclusive Hillis-Steele scan -> exclusive prefix
    int inc = cnt[t];
    exc[t] = inc;
    __syncthreads();
    for (int s = 1; s < NRANGE; s <<= 1) {
        int u = (t >= s) ? exc[t - s] : 0;
        __syncthreads();
        exc[t] += u;
        __syncthreads();
    }
    int excl = exc[t] - cnt[t];
    __syncthreads();
    exc[t] = excl;
    cur[t] = excl;
    gbase[t] = atomicAdd(&gcount[t], cnt[t]);   // 1 global atomic per (block,range)
    __syncthreads();

    // pass B: re-read (L2-hot), scatter into LDS sorted-by-range
    for (int i = t; i < n; i += K1_TPB) {
        int d = dst[base + i];
        int s = src[base + i];
        int r = (int)(((unsigned long long)d * M) >> 40);
        int dl = d - r * RW;
        int j = atomicAdd(&cur[r], 1);          // LDS
        sorted[j] = ((unsigned)dl << 17) | (unsigned)s;
        rid[j] = (unsigned char)r;
    }
    __syncthreads();

    // write phase: linear stream out of LDS -> coalesced runs per range
    for (int j = t; j < n; j += K1_TPB) {
        int r = rid[j];
        int pos = gbase[r] + (j - exc[r]);
        if (pos < cap) part[(size_t)r * cap + pos] = sorted[j];
    }
}

// ============ K2: bucket-fill in LDS, stream out coalesced (no scattered stores) ============
__global__ __launch_bounds__(1024) void build_csr(
    const unsigned int* __restrict__ part, const int* __restrict__ gcount,
    int* __restrict__ col, int* __restrict__ deg,
    int cap, int RW, int N, int maxd) {
    __shared__ int bucket[RWC * MAXD];   // 125 KB of the 160 KB/CU
    __shared__ int rank_[RWC];
    int r = blockIdx.x, t = threadIdx.x, T = blockDim.x;
    for (int i = t; i < RW; i += T) rank_[i] = 0;
    __syncthreads();

    int count = gcount[r]; if (count > cap) count = cap;
    const unsigned int* p = part + (size_t)r * cap;
    for (int i = t; i < count; i += T) {
        unsigned int v = p[i];                 // coalesced stream
        int dl = (int)(v >> 17);
        int s = (int)(v & 0x1FFFFu);
        int slot = atomicAdd(&rank_[dl], 1);   // LDS
        if (slot < maxd) bucket[dl * maxd + slot] = s;   // LDS scatter
    }
    __syncthreads();

    // stream the whole window out linearly (int4): col is node-contiguous per range
    int nbase = r * RW;
    int nvalid = N - nbase; if (nvalid > RW) nvalid = RW;
    if (nvalid <= 0) return;
    int words = nvalid * maxd;                 // multiple of 4 (maxd % 4 == 0)
    int4* dst4 = (int4*)&col[(size_t)nbase * maxd];
    const int4* src4 = (const int4*)bucket;
    int nq = words >> 2;
    for (int i = t; i < nq; i += T) dst4[i] = src4[i];
    for (int i = t; i < nvalid; i += T) {
        int rk = rank_[i];
        deg[nbase + i] = rk < maxd ? rk : maxd;
    }
}

// ============ network ============
__global__ void compute_y(const float* __restrict__ x, const float* __restrict__ W1a,
                          float* __restrict__ y, int N) {
    long long gid = (long long)blockIdx.x * blockDim.x + threadIdx.x;
    int i = (int)(gid >> 5);
    int lane = (int)(gid & 31);
    if (i >= N) return;
    float x0 = x[i * 3 + 0], x1 = x[i * 3 + 1], x2 = x[i * 3 + 2];
    float t = x0 * W1a[0 * D + lane];
    t = fmaf(x1, W1a[1 * D + lane], t);
    t = fmaf(x2, W1a[2 * D + lane], t);
    y[(size_t)i * D + lane] = t;
}

template <bool SKIP_WA>
__global__ void layer_fused(const float* __restrict__ hin, const int* __restrict__ deg,
                            const int* __restrict__ col, int maxd,
                            const float* __restrict__ Wa, const float* __restrict__ ba,
                            const float* __restrict__ Wb, const float* __restrict__ bb,
                            const float* __restrict__ g, const float* __restrict__ be,
                            const float* __restrict__ m, const float* __restrict__ v,
                            float* __restrict__ hout, int N) {
    long long gid = (long long)blockIdx.x * blockDim.x + threadIdx.x;
    int i = (int)(gid >> 5);
    int lane = (int)(gid & 31);
    if (i >= N) return;

    float acc = hin[(size_t)i * D + lane];   // self term (eps=0)
    int dg = deg[i];
    if (dg > maxd) dg = maxd;
    const int* cp = &col[(size_t)i * maxd];
    int e = 0;
    for (; e + 16 <= dg; e += 16) {          // 16 outstanding gathers for MLP
        int4 c0 = *(const int4*)&cp[e];
        int4 c1 = *(const int4*)&cp[e + 4];
        int4 c2 = *(const int4*)&cp[e + 8];
        int4 c3 = *(const int4*)&cp[e + 12];
        float a0 = hin[(size_t)c0.x * D + lane];
        float a1 = hin[(size_t)c0.y * D + lane];
        float a2 = hin[(size_t)c0.z * D + lane];
        float a3 = hin[(size_t)c0.w * D + lane];
        float a4 = hin[(size_t)c1.x * D + lane];
        float a5 = hin[(size_t)c1.y * D + lane];
        float a6 = hin[(size_t)c1.z * D + lane];
        float a7 = hin[(size_t)c1.w * D + lane];
        float a8 = hin[(size_t)c2.x * D + lane];
        float a9 = hin[(size_t)c2.y * D + lane];
        float aa = hin[(size_t)c2.z * D + lane];
        float ab = hin[(size_t)c2.w * D + lane];
        float ac = hin[(size_t)c3.x * D + lane];
        float ad = hin[(size_t)c3.y * D + lane];
        float ae = hin[(size_t)c3.z * D + lane];
        float af = hin[(size_t)c3.w * D + lane];
        acc += ((a0 + a1) + (a2 + a3)) + ((a4 + a5) + (a6 + a7)) +
               (((a8 + a9) + (aa + ab)) + ((ac + ad) + (ae + af)));
    }
    for (; e + 4 <= dg; e += 4) {
        int4 c = *(const int4*)&cp[e];
        float a0 = hin[(size_t)c.x * D + lane];
        float a1 = hin[(size_t)c.y * D + lane];
        float a2 = hin[(size_t)c.z * D + lane];
        float a3 = hin[(size_t)c.w * D + lane];
        acc += (a0 + a1) + (a2 + a3);
    }
    for (; e < dg; e++) acc += hin[(size_t)cp[e] * D + lane];

    float t;
    if (SKIP_WA) {
        t = fmaxf(acc + ba[lane], 0.f);
    } else {
        t = ba[lane];
#pragma unroll
        for (int k = 0; k < D; k++) {
            float ak = __shfl(acc, k, D);
            t = fmaf(ak, Wa[k * D + lane], t);
        }
        t = fmaxf(t, 0.f);
    }
    float o = bb[lane];
#pragma unroll
    for (int j = 0; j < D; j++) {
        float tj = __shfl(t, j, D);
        o = fmaf(tj, Wb[j * D + lane], o);
    }
    o = fmaxf(o, 0.f);
    hout[(size_t)i * D + lane] =
        g[lane] * (o - m[lane]) * rsqrtf(v[lane] + BN_EPS) + be[lane];
}

__device__ __forceinline__ int lower_bound_i(const int* a, int n, int key) {
    int lo = 0, hi = n;
    while (lo < hi) {
        int mid = (lo + hi) >> 1;
        if (a[mid] < key) lo = mid + 1; else hi = mid;
    }
    return lo;
}

__global__ void pool_head(const float* __restrict__ h, const int* __restrict__ batch,
                          const float* __restrict__ Wf1, const float* __restrict__ bf1,
                          const float* __restrict__ Wf2, const float* __restrict__ bf2,
                          float* __restrict__ out, int N, int G) {
    long long gid = (long long)blockIdx.x * blockDim.x + threadIdx.x;
    int gi = (int)(gid >> 5);
    int lane = (int)(gid & 31);
    if (gi >= G) return;
    int lo = lower_bound_i(batch, N, gi);
    int hi = lower_bound_i(batch, N, gi + 1);
    float p = 0.f;
    for (int n = lo; n < hi; n++) p += h[(size_t)n * D + lane];
    float q = bf1[lane];
#pragma unroll
    for (int j = 0; j < D; j++) {
        float pj = __shfl(p, j, D);
        q = fmaf(pj, Wf1[j * D + lane], q);
    }
    q = fmaxf(q, 0.f);
    float r = q * Wf2[lane];
#pragma unroll
    for (int off = 16; off; off >>= 1) r += __shfl_xor(r, off, D);
    if (lane == 0) out[gi] = tanhf(r + bf2[0]);
}

extern "C" void kernel_launch(void* const* d_in, const int* in_sizes, int n_in,
                              void* d_out, int out_size, void* d_ws, size_t ws_size,
                              hipStream_t stream) {
    const float* x = (const float*)d_in[0];
    const int* ei = (const int*)d_in[1];
    const int* batch = (const int*)d_in[2];
    const int E = in_sizes[1] / 2;
    const int N = in_sizes[2];
    const int G = out_size;
    const int* src = ei;
    const int* dst = ei + E;

    const float* P[3][8];
    for (int l = 0; l < 3; l++)
        for (int k = 0; k < 8; k++) P[l][k] = (const float*)d_in[3 + 8 * l + k];
    const float* Wf1 = (const float*)d_in[27];
    const float* bf1 = (const float*)d_in[28];
    const float* Wf2 = (const float*)d_in[29];
    const float* bf2 = (const float*)d_in[30];

    const int RW = (N + NRANGE - 1) / NRANGE;                    // 391 @ N=100K (<= RWC)
    const unsigned long long M = ((1ull << 40) + RW - 1) / RW;   // magic div by RW
    int mean = (E + NRANGE - 1) / NRANGE;
    int cap = mean + mean / 16 + 64;   // ~+7 sigma slack, Binomial(E, 1/256)
    cap = (cap + 3) & ~3;

    // workspace (4B units). part aliases h0 (dead until compute_y, after build done).
    float* ws = (float*)d_ws;
    size_t off = 0;
    float* h0 = ws + off; off += (size_t)N * D;
    float* h1 = ws + off; off += (size_t)N * D;
    unsigned int* part = (unsigned int*)h0;     // NRANGE*cap u32 (~13.6 MB <= h0+h1)
    int* deg = (int*)(ws + off); off += N;
    int* gcount = (int*)(ws + off); off += NRANGE;
    int* col = (int*)(ws + off);
    size_t remaining = ws_size / 4 > off ? ws_size / 4 - off : 0;
    int maxd = (int)(remaining / (size_t)N);
    if (maxd > MAXD) maxd = MAXD;
    maxd &= ~3;
    if (maxd < 4) maxd = 4;

    const int B = 256;
    long long tN32 = (long long)N * D;
    int nbp = (E + EPB - 1) / EPB;

    // ---- adjacency build: coalesced partition + LDS-bucket fill ----
    hipMemsetAsync(gcount, 0, NRANGE * sizeof(int), stream);
    build_part<<<nbp, K1_TPB, 0, stream>>>(src, dst, part, gcount, E, cap, RW, M);
    build_csr<<<NRANGE, 1024, 0, stream>>>(part, gcount, col, deg, cap, RW, N, maxd);

    // ---- layer 1 (y-space: (x+agg_x)@W1a == y+agg_y, y=x@W1a) ----
    compute_y<<<(int)((tN32 + B - 1) / B), B, 0, stream>>>(x, P[0][0], h0, N);
    layer_fused<true><<<(int)((tN32 + B - 1) / B), B, 0, stream>>>(
        h0, deg, col, maxd, P[0][0], P[0][1], P[0][2], P[0][3],
        P[0][4], P[0][5], P[0][6], P[0][7], h1, N);

    // ---- layer 2: h1 -> h0 ----
    layer_fused<false><<<(int)((tN32 + B - 1) / B), B, 0, stream>>>(
        h1, deg, col, maxd, P[1][0], P[1][1], P[1][2], P[1][3],
        P[1][4], P[1][5], P[1][6], P[1][7], h0, N);

    // ---- layer 3: h0 -> h1 ----
    layer_fused<false><<<(int)((tN32 + B - 1) / B), B, 0, stream>>>(
        h0, deg, col, maxd, P[2][0], P[2][1], P[2][2], P[2][3],
        P[2][4], P[2][5], P[2][6], P[2][7], h1, N);

    // ---- fused pool + head ----
    pool_head<<<(int)(((long long)G * D + B - 1) / B), B, 0, stream>>>(
        h1, batch, Wf1, bf1, Wf2, bf2, (float*)d_out, N, G);
}

// Round 10
// 385.839 us; speedup vs baseline: 4.9726x; 1.0706x over previous
//
#include <hip/hip_runtime.h>
#include <math.h>

#define D 32
#define BN_EPS 1e-5f
#define NRANGE 512      // dst ranges; RW = ceil(N/NRANGE) = 196 @ N=100K (fits 9 bits)
#define RWC 196         // compile-time RW bound (LDS sizing)
#define MAXD 80         // padded degree cap; Poisson(32): P(deg>80) ~ 5e-13/node
#define EPB 4096        // edges per block in build_part
#define K1_TPB 512
#define EPT (EPB / K1_TPB)   // 8 edges/thread, register-carried

// ============ K1: partition edges into per-range segments (register-carried) ============
__global__ __launch_bounds__(K1_TPB) void build_part(
    const int* __restrict__ src, const int* __restrict__ dst,
    unsigned int* __restrict__ part, int* __restrict__ gcount,
    int E, int cap, int RW, unsigned long long M) {
    __shared__ unsigned int sorted[EPB];
    __shared__ unsigned short rid[EPB];
    __shared__ int cnt[NRANGE];
    __shared__ int exc[NRANGE];
    __shared__ int cur[NRANGE];
    __shared__ int gbase[NRANGE];
    int t = threadIdx.x;
    cnt[t] = 0;                      // K1_TPB == NRANGE == 512
    __syncthreads();

    int base = blockIdx.x * EPB;
    int n = min(EPB, E - base);

    // pass A: load edges once into registers, count ranges
    unsigned int mypk[EPT];
    unsigned short myr[EPT];
#pragma unroll
    for (int k = 0; k < EPT; k++) {
        int i = t + k * K1_TPB;
        if (i < n) {
            int d = dst[base + i];
            int s = src[base + i];
            int r = (int)(((unsigned long long)d * M) >> 40);
            mypk[k] = ((unsigned)(d - r * RW) << 17) | (unsigned)s;
            myr[k] = (unsigned short)r;
            atomicAdd(&cnt[r], 1);
        } else myr[k] = 0xFFFFu;
    }
    __syncthreads();

    // inclusive Hillis-Steele scan over 512 bins -> exclusive prefix
    int inc = cnt[t];
    exc[t] = inc;
    __syncthreads();
    for (int s = 1; s < NRANGE; s <<= 1) {
        int u = (t >= s) ? exc[t - s] : 0;
        __syncthreads();
        exc[t] += u;
        __syncthreads();
    }
    int excl = exc[t] - cnt[t];
    __syncthreads();
    exc[t] = excl;
    cur[t] = excl;
    gbase[t] = atomicAdd(&gcount[t], cnt[t]);   // 1 global atomic per (block,range)
    __syncthreads();

    // pass B: scatter registers into LDS sorted-by-range
#pragma unroll
    for (int k = 0; k < EPT; k++) {
        if (myr[k] != 0xFFFFu) {
            int j = atomicAdd(&cur[myr[k]], 1);  // LDS
            sorted[j] = mypk[k];
            rid[j] = myr[k];
        }
    }
    __syncthreads();

    // write phase: linear stream out of LDS -> coalesced runs per range
    for (int j = t; j < n; j += K1_TPB) {
        int r = rid[j];
        int pos = gbase[r] + (j - exc[r]);
        if (pos < cap) part[(size_t)r * cap + pos] = sorted[j];
    }
}

// ============ K2: bucket-fill in LDS, stream out coalesced; 63 KB -> 2 blocks/CU ============
__global__ __launch_bounds__(1024) void build_csr(
    const unsigned int* __restrict__ part, const int* __restrict__ gcount,
    int* __restrict__ col, int* __restrict__ deg,
    int cap, int RW, int N, int maxd) {
    __shared__ int bucket[RWC * MAXD];   // 62.7 KB
    __shared__ int rank_[RWC];
    int r = blockIdx.x, t = threadIdx.x, T = blockDim.x;
    for (int i = t; i < RW; i += T) rank_[i] = 0;
    __syncthreads();

    int count = gcount[r]; if (count > cap) count = cap;
    const unsigned int* p = part + (size_t)r * cap;
    for (int i = t; i < count; i += T) {
        unsigned int v = p[i];                 // coalesced stream
        int dl = (int)(v >> 17);
        int s = (int)(v & 0x1FFFFu);
        int slot = atomicAdd(&rank_[dl], 1);   // LDS
        if (slot < maxd) bucket[dl * maxd + slot] = s;   // LDS scatter
    }
    __syncthreads();

    int nbase = r * RW;
    int nvalid = N - nbase; if (nvalid > RW) nvalid = RW;
    if (nvalid <= 0) return;
    int words = nvalid * maxd;                 // maxd % 4 == 0
    int4* dst4 = (int4*)&col[(size_t)nbase * maxd];
    const int4* src4 = (const int4*)bucket;
    int nq = words >> 2;
    for (int i = t; i < nq; i += T) dst4[i] = src4[i];
    for (int i = t; i < nvalid; i += T) {
        int rk = rank_[i];
        deg[nbase + i] = rk < maxd ? rk : maxd;
    }
}

// ============ network ============
__global__ void compute_y(const float* __restrict__ x, const float* __restrict__ W1a,
                          float* __restrict__ y, int N) {
    long long gid = (long long)blockIdx.x * blockDim.x + threadIdx.x;
    int i = (int)(gid >> 5);
    int lane = (int)(gid & 31);
    if (i >= N) return;
    float x0 = x[i * 3 + 0], x1 = x[i * 3 + 1], x2 = x[i * 3 + 2];
    float t = x0 * W1a[0 * D + lane];
    t = fmaf(x1, W1a[1 * D + lane], t);
    t = fmaf(x2, W1a[2 * D + lane], t);
    y[(size_t)i * D + lane] = t;
}

// POOL=true (layer 3): instead of storing hout, atomicAdd the BN output into pool[batch[i]].
template <bool SKIP_WA, bool POOL>
__global__ void layer_fused(const float* __restrict__ hin, const int* __restrict__ deg,
                            const int* __restrict__ col, int maxd,
                            const float* __restrict__ Wa, const float* __restrict__ ba,
                            const float* __restrict__ Wb, const float* __restrict__ bb,
                            const float* __restrict__ g, const float* __restrict__ be,
                            const float* __restrict__ m, const float* __restrict__ v,
                            float* __restrict__ hout, const int* __restrict__ batch,
                            int N) {
    long long gid = (long long)blockIdx.x * blockDim.x + threadIdx.x;
    int i = (int)(gid >> 5);
    int lane = (int)(gid & 31);
    if (i >= N) return;

    float acc = hin[(size_t)i * D + lane];   // self term (eps=0)
    int dg = deg[i];
    if (dg > maxd) dg = maxd;
    const int* cp = &col[(size_t)i * maxd];
    int e = 0;
    for (; e + 16 <= dg; e += 16) {          // 16 outstanding gathers for MLP
        int4 c0 = *(const int4*)&cp[e];
        int4 c1 = *(const int4*)&cp[e + 4];
        int4 c2 = *(const int4*)&cp[e + 8];
        int4 c3 = *(const int4*)&cp[e + 12];
        float a0 = hin[(size_t)c0.x * D + lane];
        float a1 = hin[(size_t)c0.y * D + lane];
        float a2 = hin[(size_t)c0.z * D + lane];
        float a3 = hin[(size_t)c0.w * D + lane];
        float a4 = hin[(size_t)c1.x * D + lane];
        float a5 = hin[(size_t)c1.y * D + lane];
        float a6 = hin[(size_t)c1.z * D + lane];
        float a7 = hin[(size_t)c1.w * D + lane];
        float a8 = hin[(size_t)c2.x * D + lane];
        float a9 = hin[(size_t)c2.y * D + lane];
        float aa = hin[(size_t)c2.z * D + lane];
        float ab = hin[(size_t)c2.w * D + lane];
        float ac = hin[(size_t)c3.x * D + lane];
        float ad = hin[(size_t)c3.y * D + lane];
        float ae = hin[(size_t)c3.z * D + lane];
        float af = hin[(size_t)c3.w * D + lane];
        acc += ((a0 + a1) + (a2 + a3)) + ((a4 + a5) + (a6 + a7)) +
               (((a8 + a9) + (aa + ab)) + ((ac + ad) + (ae + af)));
    }
    for (; e + 4 <= dg; e += 4) {
        int4 c = *(const int4*)&cp[e];
        float a0 = hin[(size_t)c.x * D + lane];
        float a1 = hin[(size_t)c.y * D + lane];
        float a2 = hin[(size_t)c.z * D + lane];
        float a3 = hin[(size_t)c.w * D + lane];
        acc += (a0 + a1) + (a2 + a3);
    }
    for (; e < dg; e++) acc += hin[(size_t)cp[e] * D + lane];

    float t;
    if (SKIP_WA) {
        t = fmaxf(acc + ba[lane], 0.f);
    } else {
        t = ba[lane];
#pragma unroll
        for (int k = 0; k < D; k++) {
            float ak = __shfl(acc, k, D);
            t = fmaf(ak, Wa[k * D + lane], t);
        }
        t = fmaxf(t, 0.f);
    }
    float o = bb[lane];
#pragma unroll
    for (int j = 0; j < D; j++) {
        float tj = __shfl(t, j, D);
        o = fmaf(tj, Wb[j * D + lane], o);
    }
    o = fmaxf(o, 0.f);
    o = g[lane] * (o - m[lane]) * rsqrtf(v[lane] + BN_EPS) + be[lane];
    if (POOL) {
        int gi = batch[i];
        atomicAdd(&hout[(size_t)gi * D + lane], o);
    } else {
        hout[(size_t)i * D + lane] = o;
    }
}

// head: relu(p@Wf1+bf1)@Wf2+bf2 -> tanh; one 32-lane group per graph
__global__ void head_kernel(const float* __restrict__ pool, const float* __restrict__ Wf1,
                            const float* __restrict__ bf1, const float* __restrict__ Wf2,
                            const float* __restrict__ bf2, float* __restrict__ out, int G) {
    long long gid = (long long)blockIdx.x * blockDim.x + threadIdx.x;
    int gi = (int)(gid >> 5);
    int lane = (int)(gid & 31);
    if (gi >= G) return;
    float p = pool[(size_t)gi * D + lane];
    float q = bf1[lane];
#pragma unroll
    for (int j = 0; j < D; j++) {
        float pj = __shfl(p, j, D);
        q = fmaf(pj, Wf1[j * D + lane], q);
    }
    q = fmaxf(q, 0.f);
    float r = q * Wf2[lane];
#pragma unroll
    for (int off = 16; off; off >>= 1) r += __shfl_xor(r, off, D);
    if (lane == 0) out[gi] = tanhf(r + bf2[0]);
}

extern "C" void kernel_launch(void* const* d_in, const int* in_sizes, int n_in,
                              void* d_out, int out_size, void* d_ws, size_t ws_size,
                              hipStream_t stream) {
    const float* x = (const float*)d_in[0];
    const int* ei = (const int*)d_in[1];
    const int* batch = (const int*)d_in[2];
    const int E = in_sizes[1] / 2;
    const int N = in_sizes[2];
    const int G = out_size;
    const int* src = ei;
    const int* dst = ei + E;

    const float* P[3][8];
    for (int l = 0; l < 3; l++)
        for (int k = 0; k < 8; k++) P[l][k] = (const float*)d_in[3 + 8 * l + k];
    const float* Wf1 = (const float*)d_in[27];
    const float* bf1 = (const float*)d_in[28];
    const float* Wf2 = (const float*)d_in[29];
    const float* bf2 = (const float*)d_in[30];

    const int RW = (N + NRANGE - 1) / NRANGE;                    // 196 @ N=100K (<= RWC)
    const unsigned long long M = ((1ull << 40) + RW - 1) / RW;   // magic div by RW
    int mean = (E + NRANGE - 1) / NRANGE;
    int cap = mean + mean / 8 + 64;    // ~+10 sigma slack, Binomial(E, 1/512)
    cap = (cap + 7) & ~7;

    // workspace (4B units). part aliases h0/h1-front (dead until compute_y).
    float* ws = (float*)d_ws;
    size_t off = 0;
    float* h0 = ws + off; off += (size_t)N * D;
    float* h1 = ws + off; off += (size_t)N * D;
    unsigned int* part = (unsigned int*)h0;     // NRANGE*cap u32 (~14.5 MB < 25.6 MB)
    int* deg = (int*)(ws + off); off += N;
    int* gcount = (int*)(ws + off); off += NRANGE;
    float* pool = ws + off; off += (size_t)G * D;
    int* col = (int*)(ws + off);
    size_t remaining = ws_size / 4 > off ? ws_size / 4 - off : 0;
    int maxd = (int)(remaining / (size_t)N);
    if (maxd > MAXD) maxd = MAXD;
    maxd &= ~3;
    if (maxd < 4) maxd = 4;

    const int B = 256;
    long long tN32 = (long long)N * D;
    int nbp = (E + EPB - 1) / EPB;

    // ---- adjacency build ----
    hipMemsetAsync(gcount, 0, NRANGE * sizeof(int), stream);
    build_part<<<nbp, K1_TPB, 0, stream>>>(src, dst, part, gcount, E, cap, RW, M);
    build_csr<<<NRANGE, 1024, 0, stream>>>(part, gcount, col, deg, cap, RW, N, maxd);

    // ---- layer 1 (y-space: (x+agg_x)@W1a == y+agg_y, y=x@W1a) ----
    compute_y<<<(int)((tN32 + B - 1) / B), B, 0, stream>>>(x, P[0][0], h0, N);
    layer_fused<true, false><<<(int)((tN32 + B - 1) / B), B, 0, stream>>>(
        h0, deg, col, maxd, P[0][0], P[0][1], P[0][2], P[0][3],
        P[0][4], P[0][5], P[0][6], P[0][7], h1, batch, N);

    // ---- layer 2: h1 -> h0 ----
    layer_fused<false, false><<<(int)((tN32 + B - 1) / B), B, 0, stream>>>(
        h1, deg, col, maxd, P[1][0], P[1][1], P[1][2], P[1][3],
        P[1][4], P[1][5], P[1][6], P[1][7], h0, batch, N);

    // ---- layer 3: h0 -> pool (fused global_add_pool via atomics) ----
    hipMemsetAsync(pool, 0, (size_t)G * D * sizeof(float), stream);
    layer_fused<false, true><<<(int)((tN32 + B - 1) / B), B, 0, stream>>>(
        h0, deg, col, maxd, P[2][0], P[2][1], P[2][2], P[2][3],
        P[2][4], P[2][5], P[2][6], P[2][7], pool, batch, N);

    // ---- head ----
    head_kernel<<<(int)(((long long)G * D + B - 1) / B), B, 0, stream>>>(
        pool, Wf1, bf1, Wf2, bf2, (float*)d_out, G);
}

// Round 11
// 375.344 us; speedup vs baseline: 5.1116x; 1.0280x over previous
//
#include <hip/hip_runtime.h>
#include <math.h>

#define D 32
#define BN_EPS 1e-5f
#define NRANGE 512      // dst ranges; RW = ceil(N/NRANGE) = 196 @ N=100K
#define RWC 196         // compile-time RW bound (LDS sizing)
#define MAXD 80         // Poisson(32): P(deg>80)~1e-11/node; P(deg>64)~2e-6/node -> 80 needed
#define EPB 8192        // edges per block in build_part (fewer blocks, longer runs)
#define K1_TPB 512
#define EPT (EPB / K1_TPB)   // 16 edges/thread, register-carried
#define PCH 8           // pool chunks per graph

// ============ K1: partition edges into per-range segments (register-carried) ============
__global__ __launch_bounds__(K1_TPB) void build_part(
    const int* __restrict__ src, const int* __restrict__ dst,
    unsigned int* __restrict__ part, int* __restrict__ gcount,
    int E, int cap, int RW, unsigned long long M) {
    __shared__ unsigned int sorted[EPB];      // 32 KB
    __shared__ unsigned short rid[EPB];       // 16 KB
    __shared__ int cnt[NRANGE];               // 8 KB total for the 4 arrays
    __shared__ int exc[NRANGE];
    __shared__ int cur[NRANGE];
    __shared__ int gbase[NRANGE];
    int t = threadIdx.x;
    cnt[t] = 0;                      // K1_TPB == NRANGE == 512
    __syncthreads();

    int base = blockIdx.x * EPB;
    int n = min(EPB, E - base);

    // pass A: load edges once into registers, count ranges
    unsigned int mypk[EPT];
    unsigned short myr[EPT];
#pragma unroll
    for (int k = 0; k < EPT; k++) {
        int i = t + k * K1_TPB;
        if (i < n) {
            int d = dst[base + i];
            int s = src[base + i];
            int r = (int)(((unsigned long long)d * M) >> 40);
            mypk[k] = ((unsigned)(d - r * RW) << 17) | (unsigned)s;
            myr[k] = (unsigned short)r;
            atomicAdd(&cnt[r], 1);
        } else myr[k] = 0xFFFFu;
    }
    __syncthreads();

    // inclusive Hillis-Steele scan over 512 bins -> exclusive prefix
    int inc = cnt[t];
    exc[t] = inc;
    __syncthreads();
    for (int s = 1; s < NRANGE; s <<= 1) {
        int u = (t >= s) ? exc[t - s] : 0;
        __syncthreads();
        exc[t] += u;
        __syncthreads();
    }
    int excl = exc[t] - cnt[t];
    __syncthreads();
    exc[t] = excl;
    cur[t] = excl;
    gbase[t] = atomicAdd(&gcount[t], cnt[t]);   // 1 global atomic per (block,range)
    __syncthreads();

    // pass B: scatter registers into LDS sorted-by-range
#pragma unroll
    for (int k = 0; k < EPT; k++) {
        if (myr[k] != 0xFFFFu) {
            int j = atomicAdd(&cur[myr[k]], 1);  // LDS
            sorted[j] = mypk[k];
            rid[j] = myr[k];
        }
    }
    __syncthreads();

    // write phase: linear stream out of LDS -> coalesced runs (~16 words) per range
    for (int j = t; j < n; j += K1_TPB) {
        int r = rid[j];
        int pos = gbase[r] + (j - exc[r]);
        if (pos < cap) part[(size_t)r * cap + pos] = sorted[j];
    }
}

// ============ K2: bucket-fill in LDS, stream out coalesced ============
__global__ __launch_bounds__(1024) void build_csr(
    const unsigned int* __restrict__ part, const int* __restrict__ gcount,
    int* __restrict__ col, int* __restrict__ deg,
    int cap, int RW, int N, int maxd) {
    __shared__ int bucket[RWC * MAXD];   // 62.7 KB
    __shared__ int rank_[RWC];
    int r = blockIdx.x, t = threadIdx.x, T = blockDim.x;
    for (int i = t; i < RW; i += T) rank_[i] = 0;
    __syncthreads();

    int count = gcount[r]; if (count > cap) count = cap;
    const unsigned int* p = part + (size_t)r * cap;
    for (int i = t; i < count; i += T) {
        unsigned int v = p[i];                 // coalesced stream
        int dl = (int)(v >> 17);
        int s = (int)(v & 0x1FFFFu);
        int slot = atomicAdd(&rank_[dl], 1);   // LDS
        if (slot < maxd) bucket[dl * maxd + slot] = s;   // LDS scatter
    }
    __syncthreads();

    int nbase = r * RW;
    int nvalid = N - nbase; if (nvalid > RW) nvalid = RW;
    if (nvalid <= 0) return;
    int words = nvalid * maxd;                 // maxd % 4 == 0
    int4* dst4 = (int4*)&col[(size_t)nbase * maxd];
    const int4* src4 = (const int4*)bucket;
    int nq = words >> 2;
    for (int i = t; i < nq; i += T) dst4[i] = src4[i];
    for (int i = t; i < nvalid; i += T) {
        int rk = rank_[i];
        deg[nbase + i] = rk < maxd ? rk : maxd;
    }
}

// ============ network ============
__global__ void compute_y(const float* __restrict__ x, const float* __restrict__ W1a,
                          float* __restrict__ y, int N) {
    long long gid = (long long)blockIdx.x * blockDim.x + threadIdx.x;
    int i = (int)(gid >> 5);
    int lane = (int)(gid & 31);
    if (i >= N) return;
    float x0 = x[i * 3 + 0], x1 = x[i * 3 + 1], x2 = x[i * 3 + 2];
    float t = x0 * W1a[0 * D + lane];
    t = fmaf(x1, W1a[1 * D + lane], t);
    t = fmaf(x2, W1a[2 * D + lane], t);
    y[(size_t)i * D + lane] = t;
}

template <bool SKIP_WA>
__global__ void layer_fused(const float* __restrict__ hin, const int* __restrict__ deg,
                            const int* __restrict__ col, int maxd,
                            const float* __restrict__ Wa, const float* __restrict__ ba,
                            const float* __restrict__ Wb, const float* __restrict__ bb,
                            const float* __restrict__ g, const float* __restrict__ be,
                            const float* __restrict__ m, const float* __restrict__ v,
                            float* __restrict__ hout, int N) {
    long long gid = (long long)blockIdx.x * blockDim.x + threadIdx.x;
    int i = (int)(gid >> 5);
    int lane = (int)(gid & 31);
    if (i >= N) return;

    float acc = hin[(size_t)i * D + lane];   // self term (eps=0)
    int dg = deg[i];
    if (dg > maxd) dg = maxd;
    const int* cp = &col[(size_t)i * maxd];
    int e = 0;
    for (; e + 16 <= dg; e += 16) {          // 16 outstanding gathers for MLP
        int4 c0 = *(const int4*)&cp[e];
        int4 c1 = *(const int4*)&cp[e + 4];
        int4 c2 = *(const int4*)&cp[e + 8];
        int4 c3 = *(const int4*)&cp[e + 12];
        float a0 = hin[(size_t)c0.x * D + lane];
        float a1 = hin[(size_t)c0.y * D + lane];
        float a2 = hin[(size_t)c0.z * D + lane];
        float a3 = hin[(size_t)c0.w * D + lane];
        float a4 = hin[(size_t)c1.x * D + lane];
        float a5 = hin[(size_t)c1.y * D + lane];
        float a6 = hin[(size_t)c1.z * D + lane];
        float a7 = hin[(size_t)c1.w * D + lane];
        float a8 = hin[(size_t)c2.x * D + lane];
        float a9 = hin[(size_t)c2.y * D + lane];
        float aa = hin[(size_t)c2.z * D + lane];
        float ab = hin[(size_t)c2.w * D + lane];
        float ac = hin[(size_t)c3.x * D + lane];
        float ad = hin[(size_t)c3.y * D + lane];
        float ae = hin[(size_t)c3.z * D + lane];
        float af = hin[(size_t)c3.w * D + lane];
        acc += ((a0 + a1) + (a2 + a3)) + ((a4 + a5) + (a6 + a7)) +
               (((a8 + a9) + (aa + ab)) + ((ac + ad) + (ae + af)));
    }
    for (; e + 4 <= dg; e += 4) {
        int4 c = *(const int4*)&cp[e];
        float a0 = hin[(size_t)c.x * D + lane];
        float a1 = hin[(size_t)c.y * D + lane];
        float a2 = hin[(size_t)c.z * D + lane];
        float a3 = hin[(size_t)c.w * D + lane];
        acc += (a0 + a1) + (a2 + a3);
    }
    for (; e < dg; e++) acc += hin[(size_t)cp[e] * D + lane];

    float t;
    if (SKIP_WA) {
        t = fmaxf(acc + ba[lane], 0.f);
    } else {
        t = ba[lane];
#pragma unroll
        for (int k = 0; k < D; k++) {
            float ak = __shfl(acc, k, D);
            t = fmaf(ak, Wa[k * D + lane], t);
        }
        t = fmaxf(t, 0.f);
    }
    float o = bb[lane];
#pragma unroll
    for (int j = 0; j < D; j++) {
        float tj = __shfl(t, j, D);
        o = fmaf(tj, Wb[j * D + lane], o);
    }
    o = fmaxf(o, 0.f);
    hout[(size_t)i * D + lane] =
        g[lane] * (o - m[lane]) * rsqrtf(v[lane] + BN_EPS) + be[lane];
}

__device__ __forceinline__ int lower_bound_i(const int* a, int n, int key) {
    int lo = 0, hi = n;
    while (lo < hi) {
        int mid = (lo + hi) >> 1;
        if (a[mid] < key) lo = mid + 1; else hi = mid;
    }
    return lo;
}

// chunked pool: G*PCH wave-groups, each sums ~len/PCH nodes of one graph, 1 atomic vector
__global__ void pool_partial(const float* __restrict__ h, const int* __restrict__ batch,
                             float* __restrict__ pool, int N, int G) {
    long long gid = (long long)blockIdx.x * blockDim.x + threadIdx.x;
    int grp = (int)(gid >> 5);
    int lane = (int)(gid & 31);
    int gi = grp / PCH;
    int c = grp - gi * PCH;
    if (gi >= G) return;
    int lo = lower_bound_i(batch, N, gi);
    int hi = lower_bound_i(batch, N, gi + 1);
    int len = hi - lo;
    if (len <= 0) return;
    int chunk = (len + PCH - 1) / PCH;
    int s = lo + c * chunk;
    int e = s + chunk; if (e > hi) e = hi;
    if (s >= e) return;
    float p = 0.f;
    for (int n = s; n < e; n++) p += h[(size_t)n * D + lane];
    atomicAdd(&pool[(size_t)gi * D + lane], p);
}

__global__ void head_kernel(const float* __restrict__ pool, const float* __restrict__ Wf1,
                            const float* __restrict__ bf1, const float* __restrict__ Wf2,
                            const float* __restrict__ bf2, float* __restrict__ out, int G) {
    long long gid = (long long)blockIdx.x * blockDim.x + threadIdx.x;
    int gi = (int)(gid >> 5);
    int lane = (int)(gid & 31);
    if (gi >= G) return;
    float p = pool[(size_t)gi * D + lane];
    float q = bf1[lane];
#pragma unroll
    for (int j = 0; j < D; j++) {
        float pj = __shfl(p, j, D);
        q = fmaf(pj, Wf1[j * D + lane], q);
    }
    q = fmaxf(q, 0.f);
    float r = q * Wf2[lane];
#pragma unroll
    for (int off = 16; off; off >>= 1) r += __shfl_xor(r, off, D);
    if (lane == 0) out[gi] = tanhf(r + bf2[0]);
}

extern "C" void kernel_launch(void* const* d_in, const int* in_sizes, int n_in,
                              void* d_out, int out_size, void* d_ws, size_t ws_size,
                              hipStream_t stream) {
    const float* x = (const float*)d_in[0];
    const int* ei = (const int*)d_in[1];
    const int* batch = (const int*)d_in[2];
    const int E = in_sizes[1] / 2;
    const int N = in_sizes[2];
    const int G = out_size;
    const int* src = ei;
    const int* dst = ei + E;

    const float* P[3][8];
    for (int l = 0; l < 3; l++)
        for (int k = 0; k < 8; k++) P[l][k] = (const float*)d_in[3 + 8 * l + k];
    const float* Wf1 = (const float*)d_in[27];
    const float* bf1 = (const float*)d_in[28];
    const float* Wf2 = (const float*)d_in[29];
    const float* bf2 = (const float*)d_in[30];

    const int RW = (N + NRANGE - 1) / NRANGE;                    // 196 @ N=100K (<= RWC)
    const unsigned long long M = ((1ull << 40) + RW - 1) / RW;   // magic div by RW
    int mean = (E + NRANGE - 1) / NRANGE;
    int cap = mean + mean / 8 + 64;    // ~+10 sigma slack, Binomial(E, 1/512)
    cap = (cap + 7) & ~7;

    // workspace (4B units). part aliases h0/h1-front (dead until compute_y).
    float* ws = (float*)d_ws;
    size_t off = 0;
    float* h0 = ws + off; off += (size_t)N * D;
    float* h1 = ws + off; off += (size_t)N * D;
    unsigned int* part = (unsigned int*)h0;     // NRANGE*cap u32 (~14.5 MB < 25.6 MB)
    int* deg = (int*)(ws + off); off += N;
    int* gcount = (int*)(ws + off); off += NRANGE;
    float* pool = ws + off; off += (size_t)G * D;
    int* col = (int*)(ws + off);
    size_t remaining = ws_size / 4 > off ? ws_size / 4 - off : 0;
    int maxd = (int)(remaining / (size_t)N);
    if (maxd > MAXD) maxd = MAXD;
    maxd &= ~3;
    if (maxd < 4) maxd = 4;

    const int B = 256;
    long long tN32 = (long long)N * D;
    int nbp = (E + EPB - 1) / EPB;

    // ---- adjacency build ----
    hipMemsetAsync(gcount, 0, NRANGE * sizeof(int), stream);
    build_part<<<nbp, K1_TPB, 0, stream>>>(src, dst, part, gcount, E, cap, RW, M);
    build_csr<<<NRANGE, 1024, 0, stream>>>(part, gcount, col, deg, cap, RW, N, maxd);

    // ---- layer 1 (y-space: (x+agg_x)@W1a == y+agg_y, y=x@W1a) ----
    compute_y<<<(int)((tN32 + B - 1) / B), B, 0, stream>>>(x, P[0][0], h0, N);
    layer_fused<true><<<(int)((tN32 + B - 1) / B), B, 0, stream>>>(
        h0, deg, col, maxd, P[0][0], P[0][1], P[0][2], P[0][3],
        P[0][4], P[0][5], P[0][6], P[0][7], h1, N);

    // ---- layer 2: h1 -> h0 ----
    layer_fused<false><<<(int)((tN32 + B - 1) / B), B, 0, stream>>>(
        h1, deg, col, maxd, P[1][0], P[1][1], P[1][2], P[1][3],
        P[1][4], P[1][5], P[1][6], P[1][7], h0, N);

    // ---- layer 3: h0 -> h1 ----
    layer_fused<false><<<(int)((tN32 + B - 1) / B), B, 0, stream>>>(
        h0, deg, col, maxd, P[2][0], P[2][1], P[2][2], P[2][3],
        P[2][4], P[2][5], P[2][6], P[2][7], h1, N);

    // ---- chunked pool + head ----
    hipMemsetAsync(pool, 0, (size_t)G * D * sizeof(float), stream);
    pool_partial<<<(int)(((long long)G * PCH * 32 + B - 1) / B), B, 0, stream>>>(
        h1, batch, pool, N, G);
    head_kernel<<<(int)(((long long)G * D + B - 1) / B), B, 0, stream>>>(
        pool, Wf1, bf1, Wf2, bf2, (float*)d_out, G);
}